// Round 5
// baseline (264.253 us; speedup 1.0000x reference)
//
#include <hip/hip_runtime.h>
#include <hip/hip_bf16.h>
#include <stdint.h>

// Problem constants (static per reference)
#define NPW   128
#define NWIN  1024
#define EPW   2048
#define NEDGE (NWIN * EPW)   // 2097152
#define BSUBJ 32
#define TMAXW 48

typedef __bf16 bf16x8_t __attribute__((ext_vector_type(8)));
typedef float  f32x4_t  __attribute__((ext_vector_type(4)));

// K1 LDS map (76.3 KB -> 2 blocks/CU):
//   MU4  @0     : u4-packed (A+I) counts [128 rows][16 u32], word-swizzled (8 KB)
//   BUF0 @8192  : activations bf16 [128][256B], byte-swizzle (row&15)<<4 (32 KB)
//   BUF1 @40960 : ping-pong partner of BUF0 (32 KB)
//   BIAS @73728 : b1a|b1b|b2a|b2b f32 (2 KB)
//   GP   @75776 : pool partials f32[128] (512 B)
//   META @76288 : {subj, pos} (16 B)
#define MU4_OFF  0
#define BUF0_OFF 8192
#define BUF1_OFF 40960
#define BIAS_OFF 73728
#define GP_OFF   75776
#define META_OFF 76288
#define K1_LDS   76304

__device__ __forceinline__ unsigned short bfbits(float v) {
  return __builtin_bit_cast(unsigned short, (__bf16)v);
}

// ---- GEMM core: 128x128x128, 8 waves as 2(row)x4(col) grid ------------------
// wave (wr,wc) owns output rows [64wr,64wr+64) x cols [32wc,32wc+32)
// acc[m][n]: m=0..3 row-subtile (16), n=0..1 col-subtile (16)

// W-GEMM: A activations from LDS (row-major swizzled), B weights from regs.
__device__ __forceinline__ void gemm_w(const char* Ab, const uint4 wreg[8],
                                       int lane, int wr, f32x4_t acc[4][2]) {
  const int sw = (lane & 15) << 4;
  #pragma unroll
  for (int kk = 0; kk < 4; ++kk) {
    const int kb = kk * 64 + (lane >> 4) * 16;
    #pragma unroll
    for (int m = 0; m < 4; ++m) {
      const int rowA = wr * 64 + m * 16 + (lane & 15);
      bf16x8_t af = *(const bf16x8_t*)(Ab + rowA * 256 + (kb ^ sw));
      #pragma unroll
      for (int n = 0; n < 2; ++n)
        acc[m][n] = __builtin_amdgcn_mfma_f32_16x16x32_bf16(
            af, __builtin_bit_cast(bf16x8_t, wreg[n * 4 + kk]), acc[m][n], 0, 0, 0);
    }
  }
}

// M-GEMM: A = u4-packed M (nibble unpack in-register), B = Y^T from LDS.
__device__ __forceinline__ void gemm_mm(const unsigned* Mw, const char* Bb,
                                        int lane, int wr, int wc, f32x4_t acc[4][2]) {
  const int g = lane >> 4;
  const int sw = (lane & 15) << 4;
  #pragma unroll
  for (int kk = 0; kk < 4; ++kk) {
    const int kb = kk * 64 + g * 16;
    bf16x8_t bv[2];
    #pragma unroll
    for (int n = 0; n < 2; ++n) {
      const int rowB = wc * 32 + n * 16 + (lane & 15);
      bv[n] = *(const bf16x8_t*)(Bb + rowB * 256 + (kb ^ sw));
    }
    #pragma unroll
    for (int m = 0; m < 4; ++m) {
      const int rowA = wr * 64 + m * 16 + (lane & 15);
      const unsigned mw = Mw[rowA * 16 + ((kk * 4 + g) ^ (lane & 15))];
      bf16x8_t af;
      #pragma unroll
      for (int e = 0; e < 8; ++e)
        af[e] = (__bf16)(float)((mw >> (4 * e)) & 15u);
      #pragma unroll
      for (int n = 0; n < 2; ++n)
        acc[m][n] = __builtin_amdgcn_mfma_f32_16x16x32_bf16(af, bv[n], acc[m][n], 0, 0, 0);
    }
  }
}

// Write C row-major (node x feature), optional bias+relu.
__device__ __forceinline__ void write_row(char* Dst, int lane, int wr, int wc,
                                          const f32x4_t acc[4][2],
                                          const float* bias, bool relu) {
  const int c = lane & 15;
  #pragma unroll
  for (int m = 0; m < 4; ++m) {
    const int r0 = wr * 64 + m * 16 + (lane >> 4) * 4;
    #pragma unroll
    for (int n = 0; n < 2; ++n) {
      const int col = wc * 32 + n * 16 + c;
      const float bvl = bias ? bias[col] : 0.f;
      #pragma unroll
      for (int j = 0; j < 4; ++j) {
        float v = acc[m][n][j] + bvl;
        if (relu) v = fmaxf(v, 0.f);
        const int row = r0 + j;
        *(__bf16*)(Dst + row * 256 + ((col * 2) ^ ((row & 15) << 4))) = (__bf16)v;
      }
    }
  }
}

// Write C transposed (feature-major), 4 rows packed per b64 store.
__device__ __forceinline__ void write_tr(char* Dst, int lane, int wr, int wc,
                                         const f32x4_t acc[4][2]) {
  const int c = lane & 15;
  #pragma unroll
  for (int m = 0; m < 4; ++m) {
    const int r0 = wr * 64 + m * 16 + (lane >> 4) * 4;
    #pragma unroll
    for (int n = 0; n < 2; ++n) {
      const int col = wc * 32 + n * 16 + c;
      unsigned long long pk = 0ull;
      #pragma unroll
      for (int j = 0; j < 4; ++j)
        pk |= ((unsigned long long)bfbits(acc[m][n][j])) << (16 * j);
      *(unsigned long long*)(Dst + col * 256 + ((r0 * 2) ^ ((col & 15) << 4))) = pk;
    }
  }
}

// ---- K0: weights f32 [in=128][out=128] -> bf16 fragment-ordered ------------
// Fragment f = wc*512 + n*256 + kk*64 + lane (uint4 each):
//   elems = W[kk*32+(lane>>4)*8 + e][wc*32+n*16+(lane&15)], e=0..7
__global__ void __launch_bounds__(256)
wprep_kernel(const float* __restrict__ w1a, const float* __restrict__ w1b,
             const float* __restrict__ w2a, const float* __restrict__ w2b,
             uint4* __restrict__ wt) {
  const float* srcs[4] = {w1a, w1b, w2a, w2b};
  const float* src = srcs[blockIdx.x];
  uint4* dst = wt + blockIdx.x * 2048;
  #pragma unroll
  for (int i = 0; i < 8; ++i) {
    const int f = i * 256 + threadIdx.x;
    const int lane = f & 63, kk = (f >> 6) & 3, n = (f >> 8) & 1, wcg = f >> 9;
    const int j = wcg * 32 + n * 16 + (lane & 15);
    const int kb = kk * 32 + (lane >> 4) * 8;
    unsigned r[4];
    #pragma unroll
    for (int e2 = 0; e2 < 4; ++e2) {
      const float a = src[(size_t)(kb + 2 * e2) * 128 + j];
      const float b = src[(size_t)(kb + 2 * e2 + 1) * 128 + j];
      r[e2] = (unsigned)bfbits(a) | ((unsigned)bfbits(b) << 16);
    }
    dst[f] = make_uint4(r[0], r[1], r[2], r[3]);
  }
}

// ---- K1: fused 2-layer GIN + mean pool + GX projection ---------------------
// (M.X).W == M.(X.W): all weight-GEMMs take natural row-major A.
__global__ void __launch_bounds__(512, 2)
gin_gnn_kernel(const float* __restrict__ x, const int* __restrict__ ei,
               const float* __restrict__ b1a, const float* __restrict__ b1b,
               const float* __restrict__ b2a, const float* __restrict__ b2b,
               const uint4* __restrict__ wfrag, const float* __restrict__ wih,
               const float* __restrict__ bih, const int* __restrict__ lengths,
               float* __restrict__ GX) {
  extern __shared__ __align__(16) char sm[];
  const int w = blockIdx.x;
  const int tid = threadIdx.x;
  const int lane = tid & 63;
  const int wv = tid >> 6, wr = wv >> 2, wc = wv & 3;

  unsigned* Mw = (unsigned*)(sm + MU4_OFF);
  char* BUF0 = sm + BUF0_OFF;
  char* BUF1 = sm + BUF1_OFF;
  float* biasb = (float*)(sm + BIAS_OFF);
  float* gp = (float*)(sm + GP_OFF);
  int* meta = (int*)(sm + META_OFF);

  // P0: zero M + pool partials
  #pragma unroll
  for (int i = tid; i < 2048; i += 512) Mw[i] = 0u;
  if (tid < 128) gp[tid] = 0.f;
  __syncthreads();

  // P1: W1a -> regs, subj/pos, edge atomics, X stage, biases
  const uint4* wf = wfrag + wc * 512 + lane;   // this wave's col-slice base
  uint4 wA[8], wB[8];
  #pragma unroll
  for (int q = 0; q < 8; ++q) wA[q] = wf[q * 64];              // W1a

  if (tid < 64) {                                              // subj/pos scan
    int L = (tid < BSUBJ) ? lengths[tid] : 0;
    int c = L;
    #pragma unroll
    for (int d = 1; d < 32; d <<= 1) {
      int u = __shfl_up(c, d, 64);
      if (tid >= d) c += u;
    }
    unsigned long long mset = __ballot(tid < BSUBJ && w < c);
    int s = (int)(__ffsll((long long)mset) - 1);
    if (tid == s) { meta[0] = s; meta[1] = w - (c - L); }
  }
  {
    const int base = w * EPW;
    #pragma unroll
    for (int rr = 0; rr < 4; ++rr) {
      const int e = base + tid + rr * 512;
      const int s = ei[e] & 127;
      const int d = ei[NEDGE + e] & 127;
      atomicAdd(&Mw[d * 16 + ((s >> 3) ^ (d & 15))], 1u << ((s & 7) * 4));
    }
    if (tid < 128) {
      const int d = tid;
      atomicAdd(&Mw[d * 16 + ((d >> 3) ^ (d & 15))], 1u << ((d & 7) * 4));
    }
  }
  {
    // X -> BUF0 row-major bf16, fully coalesced (8 x 8KB linear chunks)
    const float* xw = x + (size_t)w * 16384;
    #pragma unroll
    for (int it = 0; it < 8; ++it) {
      const int elem = it * 2048 + tid * 4;
      const float4 v = *(const float4*)(xw + elem);
      const int row = elem >> 7;
      const int colb = (elem & 127) * 2;
      unsigned long long pk = (unsigned long long)bfbits(v.x)
          | ((unsigned long long)bfbits(v.y) << 16)
          | ((unsigned long long)bfbits(v.z) << 32)
          | ((unsigned long long)bfbits(v.w) << 48);
      *(unsigned long long*)(BUF0 + row * 256 + (colb ^ ((row & 15) << 4))) = pk;
    }
  }
  {
    const float* bp = (tid < 128) ? b1a : (tid < 256) ? b1b : (tid < 384) ? b2a : b2b;
    biasb[tid] = bp[tid & 127];
  }
  __syncthreads();

  f32x4_t acc[4][2];
  #define ZACC() { _Pragma("unroll") for (int _m = 0; _m < 4; ++_m) \
                   _Pragma("unroll") for (int _n = 0; _n < 2; ++_n) \
                     acc[_m][_n] = (f32x4_t){0.f,0.f,0.f,0.f}; }

  // G1: Y1 = X @ W1a  -> BUF1 (transposed)
  ZACC(); gemm_w(BUF0, wA, lane, wr, acc);
  write_tr(BUF1, lane, wr, wc, acc);
  __syncthreads();
  // G2: H1 = relu(M @ Y1 + b1a) -> BUF0 (row-major); load W1b during
  ZACC();
  #pragma unroll
  for (int q = 0; q < 8; ++q) wB[q] = wf[2048 + q * 64];       // W1b
  gemm_mm(Mw, BUF1, lane, wr, wc, acc);
  write_row(BUF0, lane, wr, wc, acc, biasb + 0, true);
  __syncthreads();
  // G3: H1out = relu(H1 @ W1b + b1b) -> BUF1 (row-major); load W2a during
  ZACC();
  #pragma unroll
  for (int q = 0; q < 8; ++q) wA[q] = wf[4096 + q * 64];       // W2a
  gemm_w(BUF0, wB, lane, wr, acc);
  write_row(BUF1, lane, wr, wc, acc, biasb + 128, true);
  __syncthreads();
  // G4: Y2 = H1out @ W2a -> BUF0 (transposed)
  ZACC(); gemm_w(BUF1, wA, lane, wr, acc);
  write_tr(BUF0, lane, wr, wc, acc);
  __syncthreads();
  // G5: H2 = relu(M @ Y2 + b2a) -> BUF1 (row-major); load W2b during
  ZACC();
  #pragma unroll
  for (int q = 0; q < 8; ++q) wB[q] = wf[6144 + q * 64];       // W2b
  gemm_mm(Mw, BUF0, lane, wr, wc, acc);
  write_row(BUF1, lane, wr, wc, acc, biasb + 256, true);
  __syncthreads();
  // G6: H2out = relu(H2 @ W2b + b2b), fused mean pool
  ZACC(); gemm_w(BUF1, wB, lane, wr, acc);
  {
    const int c = lane & 15;
    #pragma unroll
    for (int n = 0; n < 2; ++n) {
      const int col = wc * 32 + n * 16 + c;
      const float bvl = biasb[384 + col];
      float s = 0.f;
      #pragma unroll
      for (int m = 0; m < 4; ++m)
        #pragma unroll
        for (int j = 0; j < 4; ++j) s += fmaxf(acc[m][n][j] + bvl, 0.f);
      s += __shfl_xor(s, 16);
      s += __shfl_xor(s, 32);
      if (lane < 16) atomicAdd(&gp[col], s);
    }
  }
  __syncthreads();

  // GX tail: GX[subj][pos][o] = (gp . wih[o]) / 128 + bih[o]
  if (tid < 384) {
    const float* wrow = wih + (size_t)tid * 128;
    const float4* gp4 = (const float4*)gp;
    float a0 = 0.f, a1 = 0.f, a2 = 0.f, a3 = 0.f;
    #pragma unroll
    for (int q = 0; q < 8; ++q) {
      const float4 h0 = gp4[4*q], h1 = gp4[4*q+1], h2 = gp4[4*q+2], h3 = gp4[4*q+3];
      const float4 w0 = *(const float4*)(wrow + 16*q);
      const float4 w1 = *(const float4*)(wrow + 16*q + 4);
      const float4 w2 = *(const float4*)(wrow + 16*q + 8);
      const float4 w3 = *(const float4*)(wrow + 16*q + 12);
      a0 = fmaf(w0.x,h0.x,fmaf(w0.y,h0.y,fmaf(w0.z,h0.z,fmaf(w0.w,h0.w,a0))));
      a1 = fmaf(w1.x,h1.x,fmaf(w1.y,h1.y,fmaf(w1.z,h1.z,fmaf(w1.w,h1.w,a1))));
      a2 = fmaf(w2.x,h2.x,fmaf(w2.y,h2.y,fmaf(w2.z,h2.z,fmaf(w2.w,h2.w,a2))));
      a3 = fmaf(w3.x,h3.x,fmaf(w3.y,h3.y,fmaf(w3.z,h3.z,fmaf(w3.w,h3.w,a3))));
    }
    const float dot = (a0 + a1) + (a2 + a3);
    GX[((size_t)meta[0] * TMAXW + meta[1]) * 384 + tid] = dot * (1.f / 128.f) + bih[tid];
  }
}

// ---- K3: masked GRU scan, one subject per block, 2 barriers/step -----------
__global__ void __launch_bounds__(384)
gru_kernel(const float* __restrict__ GX, const float* __restrict__ whh,
           const float* __restrict__ bhh, const float* __restrict__ wout,
           const float* __restrict__ bout, const int* __restrict__ lengths,
           float* __restrict__ outp) {
  __shared__ __align__(16) float hb[128];
  __shared__ float rb[128], zb[128];
  const int b = blockIdx.x;
  const int o = threadIdx.x;   // gate-major (r:0-127, z:128-255, n:256-383)

  float wrf[128];
  {
    const float* wr = whh + (size_t)o * 128;
    #pragma unroll
    for (int q = 0; q < 32; ++q) {
      float4 v = ((const float4*)wr)[q];
      wrf[4*q+0] = v.x; wrf[4*q+1] = v.y; wrf[4*q+2] = v.z; wrf[4*q+3] = v.w;
    }
  }
  if (o < 128) hb[o] = 0.f;
  const float bho = bhh[o];
  const int len = lengths[b];
  __syncthreads();

  float gx = (len > 0) ? GX[((size_t)b * TMAXW) * 384 + o] : 0.f;
  for (int t = 0; t < len; ++t) {
    const int tn = (t + 1 < len) ? t + 1 : t;
    const float gxn = GX[((size_t)b * TMAXW + tn) * 384 + o];
    float a0 = 0.f, a1 = 0.f, a2 = 0.f, a3 = 0.f;
    const float4* hv4 = (const float4*)hb;
    #pragma unroll
    for (int q = 0; q < 8; ++q) {
      const float4 h0 = hv4[4*q], h1 = hv4[4*q+1], h2 = hv4[4*q+2], h3 = hv4[4*q+3];
      const float* wq = wrf + 16 * q;
      a0 = fmaf(wq[0],  h0.x, a0); a0 = fmaf(wq[1],  h0.y, a0);
      a0 = fmaf(wq[2],  h0.z, a0); a0 = fmaf(wq[3],  h0.w, a0);
      a1 = fmaf(wq[4],  h1.x, a1); a1 = fmaf(wq[5],  h1.y, a1);
      a1 = fmaf(wq[6],  h1.z, a1); a1 = fmaf(wq[7],  h1.w, a1);
      a2 = fmaf(wq[8],  h2.x, a2); a2 = fmaf(wq[9],  h2.y, a2);
      a2 = fmaf(wq[10], h2.z, a2); a2 = fmaf(wq[11], h2.w, a2);
      a3 = fmaf(wq[12], h3.x, a3); a3 = fmaf(wq[13], h3.y, a3);
      a3 = fmaf(wq[14], h3.z, a3); a3 = fmaf(wq[15], h3.w, a3);
    }
    const float gh = (a0 + a1) + (a2 + a3) + bho;
    float nsave = 0.f, ghn = 0.f;
    if (o < 256) {
      const float v = 1.f / (1.f + __expf(-(gx + gh)));
      if (o < 128) rb[o] = v; else zb[o - 128] = v;
    } else {
      nsave = gx; ghn = gh;
    }
    __syncthreads();
    if (o >= 256) {
      const int oo = o - 256;
      const float r = rb[oo], z = zb[oo];
      const float pre = nsave + r * ghn;
      const float e2 = __expf(-2.f * pre);
      const float n = (1.f - e2) / (1.f + e2);
      hb[oo] = (1.f - z) * n + z * hb[oo];
    }
    __syncthreads();
    gx = gxn;
  }

  float part = (o < 128) ? hb[o] * wout[o] : 0.f;
  #pragma unroll
  for (int d = 1; d < 64; d <<= 1) part += __shfl_xor(part, d);
  __shared__ float red[6];
  if ((o & 63) == 0) red[o >> 6] = part;
  __syncthreads();
  if (o == 0) outp[b] = red[0] + red[1] + bout[0];
}

// ---- host launcher ---------------------------------------------------------
extern "C" void kernel_launch(void* const* d_in, const int* in_sizes, int n_in,
                              void* d_out, int out_size, void* d_ws, size_t ws_size,
                              hipStream_t stream) {
  const float* x    = (const float*)d_in[0];
  const int*   ei   = (const int*)d_in[1];
  const int*   len  = (const int*)d_in[3];
  const float* w1a  = (const float*)d_in[4];
  const float* b1a  = (const float*)d_in[5];
  const float* w1b  = (const float*)d_in[6];
  const float* b1b  = (const float*)d_in[7];
  const float* w2a  = (const float*)d_in[8];
  const float* b2a  = (const float*)d_in[9];
  const float* w2b  = (const float*)d_in[10];
  const float* b2b  = (const float*)d_in[11];
  const float* wih  = (const float*)d_in[12];
  const float* whh  = (const float*)d_in[13];
  const float* bih  = (const float*)d_in[14];
  const float* bhh  = (const float*)d_in[15];
  const float* wout = (const float*)d_in[16];
  const float* bout = (const float*)d_in[17];

  float* GX    = (float*)d_ws;                                       // 2.25 MB
  uint4* wfrag = (uint4*)((char*)d_ws + (size_t)BSUBJ * TMAXW * 384 * 4);  // 128 KB

  hipLaunchKernelGGL(wprep_kernel, dim3(4), dim3(256), 0, stream,
                     w1a, w1b, w2a, w2b, wfrag);
  hipLaunchKernelGGL(gin_gnn_kernel, dim3(NWIN), dim3(512), K1_LDS, stream,
                     x, ei, b1a, b1b, b2a, b2b, wfrag, wih, bih, len, GX);
  hipLaunchKernelGGL(gru_kernel, dim3(BSUBJ), dim3(384), 0, stream,
                     GX, whh, bhh, wout, bout, len, (float*)d_out);
}

// Round 8
// 251.613 us; speedup vs baseline: 1.0502x; 1.0502x over previous
//
#include <hip/hip_runtime.h>
#include <hip/hip_bf16.h>
#include <stdint.h>

// Problem constants (static per reference)
#define NPW   128
#define NWIN  1024
#define EPW   2048
#define NEDGE (NWIN * EPW)   // 2097152
#define BSUBJ 32
#define TMAXW 48

typedef __bf16 bf16x8_t __attribute__((ext_vector_type(8)));
typedef float  f32x4_t  __attribute__((ext_vector_type(4)));

// K1 LDS map (75.0 KB -> 2 blocks/CU):
//   MU4  @0     : u4-packed (A+I) counts [128 rows][16 u32], word-swizzled (8 KB)
//   B2   @8192  : activations bf16 [128][256B], byte-swizzle (row&15)<<4 (32 KB)
//   B3   @40960 : current weight W^T bf16, same swizzled layout (32 KB)
//   BIAS @73728 : b1a|b1b|b2a|b2b f32 (2 KB)
//   GP   @75776 : pool partials f32[128] (512 B)
//   META @76288 : {subj, pos} (16 B)
#define MU4_OFF  0
#define B2_OFF   8192
#define B3_OFF   40960
#define BIAS_OFF 73728
#define GP_OFF   75776
#define META_OFF 76288
#define K1_LDS   76800

__device__ __forceinline__ unsigned short bfbits(float v) {
  return __builtin_bit_cast(unsigned short, (__bf16)v);
}

// async global->LDS, 16B per lane; laddr is wave-uniform base (HW adds lane*16)
#define GLDS16(gaddr, laddr) __builtin_amdgcn_global_load_lds( \
    (const __attribute__((address_space(1))) unsigned*)(gaddr), \
    (__attribute__((address_space(3))) unsigned*)(laddr), 16, 0, 0)

// stage 32KB weights: 8 waves x 4 issues x 64 lanes x 16B
__device__ __forceinline__ void wstage(const char* src, char* dstB3, int wv, int lane) {
  #pragma unroll
  for (int p = 0; p < 4; ++p)
    GLDS16(src + wv * 4096 + p * 1024 + lane * 16, dstB3 + wv * 4096 + p * 1024);
}

// ---- GEMM: 128x128x128, 8 waves, wave rt owns rows [16rt,16rt+16) ----------
// A: row-major bf16 [i][k] swizzled.  B: B^T row-major [j][k] swizzled.
__device__ __forceinline__ void gemm_lds(const char* Ab, const char* Bb, int lane, int rt,
                                         f32x4_t acc[8]) {
  const int rowA = rt * 16 + (lane & 15);
  const int swA = (rowA & 15) << 4;
  const int swB = (lane & 15) << 4;            // (ct*16 + lane&15) & 15
  #pragma unroll
  for (int kk = 0; kk < 4; ++kk) {
    const int kb = kk * 64 + (lane >> 4) * 16; // byte offset of 8-elem k-pack
    bf16x8_t af = *(const bf16x8_t*)(Ab + rowA * 256 + (kb ^ swA));
    #pragma unroll
    for (int ct = 0; ct < 8; ++ct) {
      const int rowB = ct * 16 + (lane & 15);
      bf16x8_t bv = *(const bf16x8_t*)(Bb + rowB * 256 + (kb ^ swB));
      acc[ct] = __builtin_amdgcn_mfma_f32_16x16x32_bf16(af, bv, acc[ct], 0, 0, 0);
    }
  }
}

// A = u4-packed M (row-swizzled words), unpack nibbles -> bf16 in-register.
__device__ __forceinline__ void gemm_m(const unsigned* Mw, const char* Bb, int lane, int rt,
                                       f32x4_t acc[8]) {
  const int rowA = rt * 16 + (lane & 15);
  const int g = lane >> 4;
  const int swB = (lane & 15) << 4;
  #pragma unroll
  for (int kk = 0; kk < 4; ++kk) {
    const unsigned mw = Mw[rowA * 16 + ((kk * 4 + g) ^ (rowA & 15))];
    bf16x8_t af;
    #pragma unroll
    for (int e = 0; e < 8; ++e)
      af[e] = (__bf16)(float)((mw >> (4 * e)) & 15u);
    const int kb = kk * 64 + g * 16;
    #pragma unroll
    for (int ct = 0; ct < 8; ++ct) {
      const int rowB = ct * 16 + (lane & 15);
      bf16x8_t bv = *(const bf16x8_t*)(Bb + rowB * 256 + (kb ^ swB));
      acc[ct] = __builtin_amdgcn_mfma_f32_16x16x32_bf16(af, bv, acc[ct], 0, 0, 0);
    }
  }
}

__device__ __forceinline__ void write_row(char* Dst, int lane, int rt, const f32x4_t acc[8],
                                          const float* bias, bool relu) {
  const int r0 = rt * 16 + (lane >> 4) * 4;
  const int c = lane & 15;
  #pragma unroll
  for (int ct = 0; ct < 8; ++ct) {
    const int col = ct * 16 + c;
    const float bvl = bias ? bias[col] : 0.f;
    #pragma unroll
    for (int j = 0; j < 4; ++j) {
      float v = acc[ct][j] + bvl;
      if (relu) v = fmaxf(v, 0.f);
      const int row = r0 + j;
      *(__bf16*)(Dst + row * 256 + ((col * 2) ^ ((row & 15) << 4))) = (__bf16)v;
    }
  }
}

__device__ __forceinline__ void write_tr(char* Dst, int lane, int rt, const f32x4_t acc[8]) {
  const int r0 = rt * 16 + (lane >> 4) * 4;
  const int c = lane & 15;
  #pragma unroll
  for (int ct = 0; ct < 8; ++ct) {
    const int col = ct * 16 + c;
    unsigned long long pk = 0ull;
    #pragma unroll
    for (int j = 0; j < 4; ++j)
      pk |= ((unsigned long long)bfbits(acc[ct][j])) << (16 * j);
    *(unsigned long long*)(Dst + col * 256 + ((r0 * 2) ^ ((col & 15) << 4))) = pk;
  }
}

// ---- K0: weights f32 [in][out] -> bf16 W^T, PRE-SWIZZLED layout ------------
__global__ void __launch_bounds__(128)
wprep_kernel(const float* __restrict__ w1a, const float* __restrict__ w1b,
             const float* __restrict__ w2a, const float* __restrict__ w2b,
             unsigned* __restrict__ wt) {
  const float* srcs[4] = {w1a, w1b, w2a, w2b};
  const float* src = srcs[blockIdx.x];
  const int j = threadIdx.x;                 // output row of W^T
  unsigned* dst = wt + blockIdx.x * 8192 + j * 64;
  const int sw = (j & 15) << 2;
  #pragma unroll 8
  for (int k = 0; k < 64; ++k) {
    float a = src[(size_t)(2 * k) * 128 + j];
    float b = src[(size_t)(2 * k + 1) * 128 + j];
    dst[k ^ sw] = (unsigned)bfbits(a) | ((unsigned)bfbits(b) << 16);
  }
}

// ---- K1: fused 2-layer GIN + mean pool + GX projection ---------------------
// Uses associativity: (M.X).W == M.(X.W)  -> X staged natural row-major.
// 11 barriers: post-write syncs after G2/G5 removed (row-disjoint writes,
// next GEMM reads own rows only; weights drained at the pre-write barrier).
__global__ void __launch_bounds__(512, 2)
gin_gnn_kernel(const float* __restrict__ x, const int* __restrict__ ei,
               const float* __restrict__ b1a, const float* __restrict__ b1b,
               const float* __restrict__ b2a, const float* __restrict__ b2b,
               const char* __restrict__ wt_sw, const float* __restrict__ wih,
               const float* __restrict__ bih, const int* __restrict__ lengths,
               float* __restrict__ GX) {
  extern __shared__ __align__(16) char sm[];
  const int w = blockIdx.x;
  const int tid = threadIdx.x;
  const int lane = tid & 63;
  const int wv = tid >> 6;

  unsigned* Mw = (unsigned*)(sm + MU4_OFF);
  char* B2 = sm + B2_OFF;
  char* B3 = sm + B3_OFF;
  float* biasb = (float*)(sm + BIAS_OFF);
  float* gp = (float*)(sm + GP_OFF);
  int* meta = (int*)(sm + META_OFF);

  // P0: zero M + pool partials
  #pragma unroll
  for (int i = tid; i < 2048; i += 512) Mw[i] = 0u;
  if (tid < 128) gp[tid] = 0.f;
  __syncthreads();

  // P1: edges, X stage, biases, W1a async, subj/pos
  wstage(wt_sw, B3, wv, lane);                   // W1a -> B3 (async)
  if (tid < 64) {                                 // subj/pos wave scan
    int L = (tid < BSUBJ) ? lengths[tid] : 0;
    int c = L;
    #pragma unroll
    for (int d = 1; d < 32; d <<= 1) {
      int u = __shfl_up(c, d, 64);
      if (tid >= d) c += u;
    }
    unsigned long long mset = __ballot(tid < BSUBJ && w < c);
    int s = (int)(__ffsll((long long)mset) - 1);
    if (tid == s) { meta[0] = s; meta[1] = w - (c - L); }
  }
  {
    const int base = w * EPW;
    #pragma unroll
    for (int rr = 0; rr < 4; ++rr) {
      const int e = base + tid + rr * 512;
      const int s = ei[e] & 127;
      const int d = ei[NEDGE + e] & 127;
      atomicAdd(&Mw[d * 16 + ((s >> 3) ^ (d & 15))], 1u << ((s & 7) * 4));
    }
    if (tid < 128) {
      const int d = tid;
      atomicAdd(&Mw[d * 16 + ((d >> 3) ^ (d & 15))], 1u << ((d & 7) * 4));
    }
  }
  {
    // X -> B2 row-major bf16, fully coalesced (8 x 8KB linear chunks)
    const float* xw = x + (size_t)w * 16384;
    #pragma unroll
    for (int it = 0; it < 8; ++it) {
      const int elem = it * 2048 + tid * 4;
      const float4 v = *(const float4*)(xw + elem);
      const int row = elem >> 7;
      const int colb = (elem & 127) * 2;
      unsigned long long pk = (unsigned long long)bfbits(v.x)
          | ((unsigned long long)bfbits(v.y) << 16)
          | ((unsigned long long)bfbits(v.z) << 32)
          | ((unsigned long long)bfbits(v.w) << 48);
      *(unsigned long long*)(B2 + row * 256 + (colb ^ ((row & 15) << 4))) = pk;
    }
  }
  {
    const float* bp = (tid < 128) ? b1a : (tid < 256) ? b1b : (tid < 384) ? b2a : b2b;
    biasb[tid] = bp[tid & 127];
  }
  __syncthreads();                               // drains vmcnt: W1a landed

  f32x4_t acc[8];
  #define ZACC() { _Pragma("unroll") for (int q = 0; q < 8; ++q) acc[q] = (f32x4_t){0.f,0.f,0.f,0.f}; }

  // G1: Y1 = X @ W1a   (A natural row-major)
  ZACC(); gemm_lds(B2, B3, lane, wv, acc);
  __syncthreads();
  write_tr(B2, lane, wv, acc);                   // Y1^T feature-major
  wstage(wt_sw + 32768, B3, wv, lane);           // W1b (B3 free after G1)
  __syncthreads();
  // G2: H1 = relu(M @ Y1 + b1a)
  ZACC(); gemm_m(Mw, B2, lane, wv, acc);
  __syncthreads();                               // all waves done reading Y1^T; W1b drained
  write_row(B2, lane, wv, acc, biasb + 0, true);
  // no barrier: G3 reads only own rows (written above) + drained W1b
  // G3: H1out = relu(H1 @ W1b + b1b)
  ZACC(); gemm_lds(B2, B3, lane, wv, acc);
  __syncthreads();
  write_row(B2, lane, wv, acc, biasb + 128, true);
  wstage(wt_sw + 65536, B3, wv, lane);           // W2a
  __syncthreads();                               // W2a drained before G4
  // G4: Y2 = H1out @ W2a
  ZACC(); gemm_lds(B2, B3, lane, wv, acc);
  __syncthreads();
  write_tr(B2, lane, wv, acc);                   // Y2^T
  wstage(wt_sw + 98304, B3, wv, lane);           // W2b
  __syncthreads();
  // G5: H2 = relu(M @ Y2 + b2a)
  ZACC(); gemm_m(Mw, B2, lane, wv, acc);
  __syncthreads();                               // all waves done reading Y2^T; W2b drained
  write_row(B2, lane, wv, acc, biasb + 256, true);
  // no barrier: G6 reads only own rows + drained W2b
  // G6: H2out = relu(H2 @ W2b + b2b), fused mean pool
  ZACC(); gemm_lds(B2, B3, lane, wv, acc);
  {
    const int c = lane & 15;
    #pragma unroll
    for (int ct = 0; ct < 8; ++ct) {
      const int col = ct * 16 + c;
      const float bvl = biasb[384 + col];
      float s = 0.f;
      #pragma unroll
      for (int j = 0; j < 4; ++j) s += fmaxf(acc[ct][j] + bvl, 0.f);
      s += __shfl_xor(s, 16);
      s += __shfl_xor(s, 32);
      if (lane < 16) atomicAdd(&gp[col], s);
    }
  }
  __syncthreads();

  // GX tail: GX[subj][pos][o] = (gp . wih[o]) / 128 + bih[o]
  if (tid < 384) {
    const float* wrow = wih + (size_t)tid * 128;
    const float4* gp4 = (const float4*)gp;
    float a0 = 0.f, a1 = 0.f, a2 = 0.f, a3 = 0.f;
    #pragma unroll
    for (int q = 0; q < 8; ++q) {
      const float4 h0 = gp4[4*q], h1 = gp4[4*q+1], h2 = gp4[4*q+2], h3 = gp4[4*q+3];
      const float4 w0 = *(const float4*)(wrow + 16*q);
      const float4 w1 = *(const float4*)(wrow + 16*q + 4);
      const float4 w2 = *(const float4*)(wrow + 16*q + 8);
      const float4 w3 = *(const float4*)(wrow + 16*q + 12);
      a0 = fmaf(w0.x,h0.x,fmaf(w0.y,h0.y,fmaf(w0.z,h0.z,fmaf(w0.w,h0.w,a0))));
      a1 = fmaf(w1.x,h1.x,fmaf(w1.y,h1.y,fmaf(w1.z,h1.z,fmaf(w1.w,h1.w,a1))));
      a2 = fmaf(w2.x,h2.x,fmaf(w2.y,h2.y,fmaf(w2.z,h2.z,fmaf(w2.w,h2.w,a2))));
      a3 = fmaf(w3.x,h3.x,fmaf(w3.y,h3.y,fmaf(w3.z,h3.z,fmaf(w3.w,h3.w,a3))));
    }
    const float dot = (a0 + a1) + (a2 + a3);
    GX[((size_t)meta[0] * TMAXW + meta[1]) * 384 + tid] = dot * (1.f / 128.f) + bih[tid];
  }
}

// ---- K3: masked GRU scan, one subject per block ----------------------------
// h broadcast via v_readlane from registers (no LDS pipe in the dot product).
#define RL(v, l) __builtin_bit_cast(float, __builtin_amdgcn_readlane(__builtin_bit_cast(int, (v)), (l)))

__global__ void __launch_bounds__(384)
gru_kernel(const float* __restrict__ GX, const float* __restrict__ whh,
           const float* __restrict__ bhh, const float* __restrict__ wout,
           const float* __restrict__ bout, const int* __restrict__ lengths,
           float* __restrict__ outp) {
  __shared__ __align__(8) float hb[128];
  __shared__ float rb[128], zb[128];
  const int b = blockIdx.x;
  const int o = threadIdx.x;   // gate-major (r:0-127, z:128-255, n:256-383)
  const int lane = o & 63;

  float wrf[128];
  {
    const float* wr = whh + (size_t)o * 128;
    #pragma unroll
    for (int q = 0; q < 32; ++q) {
      float4 v = ((const float4*)wr)[q];
      wrf[4*q+0] = v.x; wrf[4*q+1] = v.y; wrf[4*q+2] = v.z; wrf[4*q+3] = v.w;
    }
  }
  if (o < 128) hb[o] = 0.f;
  const float bho = bhh[o];
  const int len = lengths[b];
  __syncthreads();

  float2 hv = make_float2(0.f, 0.f);   // h[2*lane], h[2*lane+1], replicated per wave
  float gx = (len > 0) ? GX[((size_t)b * TMAXW) * 384 + o] : 0.f;
  for (int t = 0; t < len; ++t) {
    const int tn = (t + 1 < len) ? t + 1 : t;
    const float gxn = GX[((size_t)b * TMAXW + tn) * 384 + o];
    // gh[o] = whh[o] . h : 128 readlane + 128 fma, 4 independent chains
    float a0 = 0.f, a1 = 0.f, a2 = 0.f, a3 = 0.f;
    #pragma unroll
    for (int l4 = 0; l4 < 16; ++l4) {
      const int l0 = 4*l4, l1 = 4*l4+1, l2 = 4*l4+2, l3 = 4*l4+3;
      a0 = fmaf(wrf[2*l0],   RL(hv.x, l0), a0);
      a0 = fmaf(wrf[2*l0+1], RL(hv.y, l0), a0);
      a1 = fmaf(wrf[2*l1],   RL(hv.x, l1), a1);
      a1 = fmaf(wrf[2*l1+1], RL(hv.y, l1), a1);
      a2 = fmaf(wrf[2*l2],   RL(hv.x, l2), a2);
      a2 = fmaf(wrf[2*l2+1], RL(hv.y, l2), a2);
      a3 = fmaf(wrf[2*l3],   RL(hv.x, l3), a3);
      a3 = fmaf(wrf[2*l3+1], RL(hv.y, l3), a3);
    }
    const float gh = (a0 + a1) + (a2 + a3) + bho;
    if (o < 256) {
      const float v = 1.f / (1.f + __expf(-(gx + gh)));
      if (o < 128) rb[o] = v; else zb[o - 128] = v;
    }
    __syncthreads();
    if (o >= 256) {
      const int oo = o - 256;
      const float r = rb[oo], z = zb[oo];
      const float pre = gx + r * gh;
      const float e2 = __expf(-2.f * pre);
      const float n = (1.f - e2) / (1.f + e2);
      hb[oo] = (1.f - z) * n + z * hb[oo];
    }
    __syncthreads();
    hv = *(const float2*)(hb + 2 * lane);
    gx = gxn;
  }

  float part = (o < 128) ? hb[o] * wout[o] : 0.f;
  #pragma unroll
  for (int d = 1; d < 64; d <<= 1) part += __shfl_xor(part, d);
  __shared__ float red[6];
  if ((o & 63) == 0) red[o >> 6] = part;
  __syncthreads();
  if (o == 0) outp[b] = red[0] + red[1] + bout[0];
}

// ---- host launcher ---------------------------------------------------------
extern "C" void kernel_launch(void* const* d_in, const int* in_sizes, int n_in,
                              void* d_out, int out_size, void* d_ws, size_t ws_size,
                              hipStream_t stream) {
  const float* x    = (const float*)d_in[0];
  const int*   ei   = (const int*)d_in[1];
  const int*   len  = (const int*)d_in[3];
  const float* w1a  = (const float*)d_in[4];
  const float* b1a  = (const float*)d_in[5];
  const float* w1b  = (const float*)d_in[6];
  const float* b1b  = (const float*)d_in[7];
  const float* w2a  = (const float*)d_in[8];
  const float* b2a  = (const float*)d_in[9];
  const float* w2b  = (const float*)d_in[10];
  const float* b2b  = (const float*)d_in[11];
  const float* wih  = (const float*)d_in[12];
  const float* whh  = (const float*)d_in[13];
  const float* bih  = (const float*)d_in[14];
  const float* bhh  = (const float*)d_in[15];
  const float* wout = (const float*)d_in[16];
  const float* bout = (const float*)d_in[17];

  float*    GX    = (float*)d_ws;                                // 2.25 MB
  unsigned* wt_sw = (unsigned*)((char*)d_ws + (size_t)BSUBJ * TMAXW * 384 * 4);

  hipLaunchKernelGGL(wprep_kernel, dim3(4), dim3(128), 0, stream,
                     w1a, w1b, w2a, w2b, wt_sw);
  hipLaunchKernelGGL(gin_gnn_kernel, dim3(NWIN), dim3(512), K1_LDS, stream,
                     x, ei, b1a, b1b, b2a, b2b, (const char*)wt_sw,
                     wih, bih, len, GX);
  hipLaunchKernelGGL(gru_kernel, dim3(BSUBJ), dim3(384), 0, stream,
                     GX, whh, bhh, wout, bout, len, (float*)d_out);
}